// Round 7
// baseline (816.799 us; speedup 1.0000x reference)
//
#include <hip/hip_runtime.h>
#include <hip/hip_bf16.h>

#define C 32
#define LN_EPS 1e-5f
#define LSP_W 128          // superpoints per bucket
#define LSP_SH 7
#define BMAX 512           // max buckets supported (S <= 65536)
#define PPB 2048           // points per partition block
#define PPT 8              // points per thread in P0/P1 (PPB/256)

// ---------------- P0: coarse bucket histogram --------------------------------
__global__ __launch_bounds__(256) void p0_hist(
    const int* __restrict__ sp_ids, int* __restrict__ hist, int n, int B)
{
    __shared__ int h[BMAX];
    for (int i = threadIdx.x; i < BMAX; i += 256) h[i] = 0;
    __syncthreads();
    int base = blockIdx.x * PPB;
    #pragma unroll
    for (int k = 0; k < PPT; ++k) {
        int p = base + threadIdx.x + k * 256;
        if (p < n) atomicAdd(&h[sp_ids[p] >> LSP_SH], 1);
    }
    __syncthreads();
    for (int i = threadIdx.x; i < B; i += 256) {
        int v = h[i];
        if (v) atomicAdd(&hist[i], v);
    }
}

// ---------------- P0b: scan bucket totals -> base, cursor --------------------
__global__ __launch_bounds__(BMAX) void p0b_scan(
    const int* __restrict__ hist, int* __restrict__ base_,
    int* __restrict__ cursor, int B)
{
    __shared__ int lds[BMAX];
    int t = threadIdx.x;
    int v = (t < B) ? hist[t] : 0;
    lds[t] = v;
    __syncthreads();
    for (int d = 1; d < BMAX; d <<= 1) {
        int add = (t >= d) ? lds[t - d] : 0;
        __syncthreads();
        lds[t] += add;
        __syncthreads();
    }
    if (t < B) {
        int ex = lds[t] - v;
        base_[t]  = ex;
        cursor[t] = ex;
    }
}

// ---------------- P1: partition records into bucket order --------------------
// record = {x, y, z, w = v | (lsp<<21)}   (v < 2^21, lsp < 128)
__global__ __launch_bounds__(256) void p1_partition(
    const int* __restrict__ sp_ids, const float* __restrict__ xyz,
    const int* __restrict__ p2v, int* __restrict__ cursor,
    uint4* __restrict__ recs, int n, int B)
{
    __shared__ int cnt[BMAX];
    __shared__ int lbase[BMAX];
    __shared__ int gbase[BMAX];
    __shared__ int scan2[256];
    __shared__ uint4 stage[PPB];
    __shared__ unsigned gpos[PPB];

    int t = threadIdx.x;
    int blk0 = blockIdx.x * PPB;
    int m = n - blk0; if (m > PPB) m = PPB;

    for (int i = t; i < BMAX; i += 256) cnt[i] = 0;
    __syncthreads();

    // pass A: bucket + block-local rank per point
    unsigned code[PPT];
    #pragma unroll
    for (int k = 0; k < PPT; ++k) {
        int idx = t + k * 256;
        code[k] = 0xFFFFFFFFu;
        if (idx < m) {
            int sp  = sp_ids[blk0 + idx];
            int b   = sp >> LSP_SH;            // 9 bits
            int lsp = sp & (LSP_W - 1);        // 7 bits
            int lr  = atomicAdd(&cnt[b], 1);   // 11 bits (< 2048)
            code[k] = ((unsigned)b << 18) | ((unsigned)lsp << 11) | (unsigned)lr;
        }
    }
    __syncthreads();

    // block-local exclusive scan of cnt (512 bins via 256 threads x 2)
    int c0 = cnt[2 * t], c1 = cnt[2 * t + 1];
    int pairsum = c0 + c1;
    scan2[t] = pairsum;
    __syncthreads();
    for (int d = 1; d < 256; d <<= 1) {
        int add = (t >= d) ? scan2[t - d] : 0;
        __syncthreads();
        scan2[t] += add;
        __syncthreads();
    }
    int exc = scan2[t] - pairsum;
    lbase[2 * t]     = exc;
    lbase[2 * t + 1] = exc + c0;
    __syncthreads();

    // reserve global space per bucket (one atomic per nonzero bucket)
    for (int i = t; i < B; i += 256) {
        int cb = cnt[i];
        gbase[i] = cb ? atomicAdd(&cursor[i], cb) : 0;
    }
    __syncthreads();

    // pass B: build records into LDS in bucket-sorted order
    #pragma unroll
    for (int k = 0; k < PPT; ++k) {
        int idx = t + k * 256;
        if (idx < m) {
            unsigned cd = code[k];
            int b   = cd >> 18;
            int lsp = (cd >> 11) & 127;
            int lr  = cd & 0x7FF;
            int p   = blk0 + idx;
            unsigned w = (unsigned)p2v[p] | ((unsigned)lsp << 21);
            uint4 r = make_uint4(__float_as_uint(xyz[3 * p + 0]),
                                 __float_as_uint(xyz[3 * p + 1]),
                                 __float_as_uint(xyz[3 * p + 2]), w);
            int slot = lbase[b] + lr;
            stage[slot] = r;
            gpos[slot]  = (unsigned)(gbase[b] + lr);
        }
    }
    __syncthreads();

    // write out in sorted order: consecutive lanes -> (mostly) consecutive dst
    for (int s = t; s < m; s += 256)
        recs[gpos[s]] = stage[s];
}

// ---------------- P2: per-bucket MLP + gather + LDS accumulate + mean --------
__global__ __launch_bounds__(256) void p2_accumulate(
    const uint4* __restrict__ recs,
    const float* __restrict__ voxel_feats,
    const float* __restrict__ W1, const float* __restrict__ b1,
    const float* __restrict__ gamma, const float* __restrict__ beta,
    const float* __restrict__ W2, const float* __restrict__ b2,
    const int* __restrict__ base_, const int* __restrict__ hist,
    float* __restrict__ out_x, float* __restrict__ out_xyz, int S)
{
    // per-sp bins: 32 acc + 3 xyz + 1 count, stride 37 (coprime with 32 banks)
    __shared__ float bins[LSP_W * 37];
    int b = blockIdx.x;
    for (int i = threadIdx.x; i < LSP_W * 37; i += 256) bins[i] = 0.f;
    __syncthreads();

    int start = base_[b];
    int cntb  = hist[b];

    for (int i = threadIdx.x; i < cntb; i += 256) {
        uint4 r = recs[start + i];
        int v   = (int)(r.w & 0x1FFFFFu);
        int lsp = (int)((r.w >> 21) & 127u);

        // issue the one compulsory random gather early
        const float4* vrow = (const float4*)(voxel_feats + (size_t)v * C);
        float4 g0 = vrow[0], g1 = vrow[1], g2 = vrow[2], g3 = vrow[3];
        float4 g4 = vrow[4], g5 = vrow[5], g6 = vrow[6], g7 = vrow[7];

        float x0 = __uint_as_float(r.x);
        float x1 = __uint_as_float(r.y);
        float x2 = __uint_as_float(r.z);

        // Linear(3,32)
        float h[C];
        #pragma unroll
        for (int c = 0; c < C; ++c)
            h[c] = fmaf(x0, W1[c], fmaf(x1, W1[C + c], fmaf(x2, W1[2 * C + c], b1[c])));

        // LayerNorm(32)
        float s = 0.f, s2 = 0.f;
        #pragma unroll
        for (int c = 0; c < C; ++c) { s += h[c]; s2 += h[c] * h[c]; }
        float mu   = s * (1.0f / C);
        float var  = fmaf(-mu, mu, s2 * (1.0f / C));
        float rstd = rsqrtf(var + LN_EPS);
        #pragma unroll
        for (int c = 0; c < C; ++c)
            h[c] = fmaxf(fmaf((h[c] - mu) * rstd, gamma[c], beta[c]), 0.0f);

        // acc = b2 + h @ W2
        float acc[C];
        #pragma unroll
        for (int c = 0; c < C; ++c) acc[c] = b2[c];
        #pragma unroll
        for (int k = 0; k < C; ++k) {
            float rk = h[k];
            #pragma unroll
            for (int c = 0; c < C; ++c)
                acc[c] = fmaf(rk, W2[k * C + c], acc[c]);
        }

        // + gathered voxel row
        float gf[C] = { g0.x,g0.y,g0.z,g0.w, g1.x,g1.y,g1.z,g1.w,
                        g2.x,g2.y,g2.z,g2.w, g3.x,g3.y,g3.z,g3.w,
                        g4.x,g4.y,g4.z,g4.w, g5.x,g5.y,g5.z,g5.w,
                        g6.x,g6.y,g6.z,g6.w, g7.x,g7.y,g7.z,g7.w };

        float* bin = &bins[lsp * 37];
        #pragma unroll
        for (int c = 0; c < C; ++c) atomicAdd(&bin[c], acc[c] + gf[c]);
        atomicAdd(&bin[32], x0);
        atomicAdd(&bin[33], x1);
        atomicAdd(&bin[34], x2);
        atomicAdd(&bin[35], 1.0f);
    }
    __syncthreads();

    // mean + writeout
    int sp0 = b << LSP_SH;
    for (int i = threadIdx.x; i < LSP_W * C; i += 256) {
        int lsp = i >> 5, c = i & 31;
        int sp = sp0 + lsp;
        if (sp < S) {
            float inv = 1.0f / fmaxf(bins[lsp * 37 + 35], 1.0f);
            out_x[(size_t)sp * C + c] = bins[lsp * 37 + c] * inv;
        }
    }
    for (int i = threadIdx.x; i < LSP_W * 3; i += 256) {
        int lsp = i / 3, k = i - lsp * 3;
        int sp = sp0 + lsp;
        if (sp < S) {
            float inv = 1.0f / fmaxf(bins[lsp * 37 + 35], 1.0f);
            out_xyz[(size_t)sp * 3 + k] = bins[lsp * 37 + 32 + k] * inv;
        }
    }
}

extern "C" void kernel_launch(void* const* d_in, const int* in_sizes, int n_in,
                              void* d_out, int out_size, void* d_ws, size_t ws_size,
                              hipStream_t stream)
{
    const float* voxel_feats = (const float*)d_in[0];
    const float* xyz         = (const float*)d_in[1];
    const float* W1          = (const float*)d_in[2];
    const float* b1          = (const float*)d_in[3];
    const float* gamma       = (const float*)d_in[4];
    const float* beta        = (const float*)d_in[5];
    const float* W2          = (const float*)d_in[6];
    const float* b2          = (const float*)d_in[7];
    const int*   p2v         = (const int*)d_in[8];
    const int*   sp_ids      = (const int*)d_in[9];

    const int n_pts = in_sizes[8];
    const int S     = out_size / 35;
    const int B     = (S + LSP_W - 1) >> LSP_SH;   // 391 for S=50000

    float* out_x   = (float*)d_out;
    float* out_xyz = out_x + (size_t)S * C;

    // ws layout: hist[BMAX] | base[BMAX] | cursor[BMAX] | recs[n_pts] (16-B aligned)
    int* hist   = (int*)d_ws;
    int* base_  = hist + BMAX;
    int* cursor = base_ + BMAX;
    uint4* recs = (uint4*)((char*)d_ws + 3 * BMAX * sizeof(int));

    int nblk = (n_pts + PPB - 1) / PPB;

    hipMemsetAsync(hist, 0, BMAX * sizeof(int), stream);
    p0_hist<<<nblk, 256, 0, stream>>>(sp_ids, hist, n_pts, B);
    p0b_scan<<<1, BMAX, 0, stream>>>(hist, base_, cursor, B);
    p1_partition<<<nblk, 256, 0, stream>>>(sp_ids, xyz, p2v, cursor, recs, n_pts, B);
    p2_accumulate<<<B, 256, 0, stream>>>(
        recs, voxel_feats, W1, b1, gamma, beta, W2, b2,
        base_, hist, out_x, out_xyz, S);
}